// Round 14
// baseline (172.540 us; speedup 1.0000x reference)
//
#include <hip/hip_runtime.h>

typedef unsigned short u16;
typedef _Float16 f16;

using half8   = __attribute__((ext_vector_type(8))) _Float16;
using f32x4   = __attribute__((ext_vector_type(4))) float;
using ushort8 = __attribute__((ext_vector_type(8))) unsigned short;
using us4     = __attribute__((ext_vector_type(4))) unsigned short;
using float4v = __attribute__((ext_vector_type(4))) float;

#define B_  8
#define S_  2048
#define D_  512

#define VMCNT(N)  asm volatile("s_waitcnt vmcnt(" #N ")" ::: "memory")
#define LGKM0()   asm volatile("s_waitcnt lgkmcnt(0)" ::: "memory")
#define SBAR()    asm volatile("s_barrier" ::: "memory")

__device__ __forceinline__ u16 f2h(float f) {
  f16 h = (f16)f;
  u16 u;
  __builtin_memcpy(&u, &h, 2);
  return u;
}

__device__ __forceinline__ float h2f(u16 h) {
  f16 x;
  __builtin_memcpy(&x, &h, 2);
  return (float)x;
}

__device__ __forceinline__ void stage16(const void* g, void* l) {
  __builtin_amdgcn_global_load_lds((const __attribute__((address_space(1))) void*)g,
                                   (__attribute__((address_space(3))) void*)l,
                                   16, 0, 0);
}

// XCD-aware bijective remap (all grids have nwg % 8 == 0).
__device__ __forceinline__ void xcd_remap(int& bx, int& by, int& bz) {
  const int lin = ((int)blockIdx.z * (int)gridDim.y + (int)blockIdx.y) * (int)gridDim.x
                  + (int)blockIdx.x;
  const int nwg = (int)gridDim.x * (int)gridDim.y * (int)gridDim.z;
  const int swz = (lin & 7) * (nwg >> 3) + (lin >> 3);
  bx = swz % (int)gridDim.x;
  const int tmp = swz / (int)gridDim.x;
  by = tmp % (int)gridDim.y;
  bz = tmp / (int)gridDim.y;
}

// ===================== round-5 core: 128x128, BK=32, 3-buf (proj) =====================
__device__ __forceinline__ void gemm128(const u16* __restrict__ A, const u16* __restrict__ B,
                                        int K, int m0, int n0,
                                        u16* lds, f32x4 acc[4][4]) {
  constexpr int TILE_ELEMS = 4096;
  constexpr int BUF_ELEMS  = 8192;
  const int tid  = threadIdx.x;
  const int lane = tid & 63;
  const int wave = tid >> 6;
  const int wr = wave >> 1, wc = wave & 1;
  const int fr   = lane & 15;
  const int fgrp = lane >> 4;

  int sr[2], sc[2];
  #pragma unroll
  for (int s = 0; s < 2; ++s) {
    const int p    = tid * 16 + s * 4096;
    const int R    = p >> 7;
    const int slot = (p >> 4) & 7;
    const int s0   = slot ^ (R & 7);
    sr[s] = 2 * R + (s0 >> 2);
    sc[s] = (s0 & 3) * 8;
  }

  int offA[4], offB[4];
  #pragma unroll
  for (int m = 0; m < 4; ++m) {
    const int ra = wr * 64 + m * 16 + fr;
    const int Ra = ra >> 1;
    offA[m] = Ra * 128 + (((((ra & 1) << 2) | fgrp) ^ (Ra & 7)) << 4);
    const int rb = wc * 64 + m * 16 + fr;
    const int Rb = rb >> 1;
    offB[m] = Rb * 128 + (((((rb & 1) << 2) | fgrp) ^ (Rb & 7)) << 4);
  }

  const f32x4 vzero = {0.f, 0.f, 0.f, 0.f};
  #pragma unroll
  for (int m = 0; m < 4; ++m)
    #pragma unroll
    for (int n = 0; n < 4; ++n)
      acc[m][n] = vzero;

  const int T = K / 32;

  auto STAGE = [&](int t, u16* buf) {
    #pragma unroll
    for (int s = 0; s < 2; ++s) {
      stage16(A + (size_t)(m0 + sr[s]) * K + t * 32 + sc[s],
              buf + s * 2048 + wave * 512);
      stage16(B + (size_t)(n0 + sr[s]) * K + t * 32 + sc[s],
              buf + TILE_ELEMS + s * 2048 + wave * 512);
    }
  };

  STAGE(0, lds);
  STAGE(1, lds + BUF_ELEMS);

  int r = 0;
  for (int u = 0; u < T; ++u) {
    if (u + 1 < T) {
      asm volatile("s_waitcnt vmcnt(4)\n\ts_barrier" ::: "memory");
    } else {
      asm volatile("s_waitcnt vmcnt(0)\n\ts_barrier" ::: "memory");
    }
    const u16* buf = lds + r * BUF_ELEMS;
    half8 a[4], b[4];
    #pragma unroll
    for (int m = 0; m < 4; ++m)
      a[m] = *(const half8*)((const char*)buf + offA[m]);
    #pragma unroll
    for (int n = 0; n < 4; ++n)
      b[n] = *(const half8*)((const char*)(buf + TILE_ELEMS) + offB[n]);
    if (u + 2 < T)
      STAGE(u + 2, lds + (r == 0 ? 2 : r - 1) * BUF_ELEMS);
    __builtin_amdgcn_s_setprio(1);
    #pragma unroll
    for (int m = 0; m < 4; ++m)
      #pragma unroll
      for (int n = 0; n < 4; ++n)
        acc[m][n] = __builtin_amdgcn_mfma_f32_16x16x32_f16(a[m], b[n], acc[m][n], 0, 0, 0);
    __builtin_amdgcn_s_setprio(0);
    r = (r == 2) ? 0 : r + 1;
  }
}

// ===================== coreWS: wave-specialized producer/consumer (qk, pv) =====================
// Block = 8 waves: waves 0-3 consumers (2x2, per-wave 64x128), waves 4-7 producers.
// Tile: BM=128 x BN=256, BK=32. LDS: 3 buffers x 24 KB = 72 KB; buffer =
// [A image 128x32][B image 256x32], paired-row swizzle (PMC-verified):
// global (row r, 8-elem chunk g) -> image byte (r>>1)*128 + ((((r&1)<<2)|g)^((r>>1)&7))*16.
// Producers per tile t: {issue 6 gload_lds of tile t+2 -> buf[(t+2)%3];
//   vmcnt(6) [tile t+1 landed, t+2 in flight; vmcnt(0) in tail]; s_barrier}.
// Consumers per tile t: {s_barrier; ds_read tile t+1 frags (buf already full -
//   read-ahead hides LDS latency under MFMA); MFMA tile t; lgkmcnt(0)}.
// Safety: producer own-vmcnt-before-barrier publishes tile t+1 chip-wide at
// bar_t (r8-verified discipline); consumer lgkm(0)-before-barrier drains reads
// of buf[(t-1)%3] before producer re-issues into it (3-buffer reuse safe).
// Barrier counts: NT for both roles; none after the loop.
constexpr int WS_BUFE = 12288;   // elems per buffer (24 KB)
constexpr int WS_ABYT = 8192;    // A image bytes

__device__ __forceinline__ void ws_producer(const u16* __restrict__ A,
                                            const u16* __restrict__ B,
                                            int K, int m0, int n0, u16* lds) {
  const int lane = threadIdx.x & 63;
  const int pw   = (threadIdx.x >> 6) - 4;   // 0..3
  const u16* src[6];
  int dstE[6];
  #pragma unroll
  for (int i = 0; i < 6; ++i) {
    const int gidx = pw * 6 + i;
    const int pt   = gidx * 1024 + lane * 16;   // byte in buffer
    const bool isA = (pt < WS_ABYT);
    const int q    = isA ? pt : (pt - WS_ABYT);
    const int R    = q >> 7;
    const int s0   = ((q >> 4) & 7) ^ (R & 7);
    const int row  = 2 * R + (s0 >> 2);
    const int col  = (s0 & 3) * 8;
    src[i]  = (isA ? A + (size_t)(m0 + row) * K : B + (size_t)(n0 + row) * K) + col;
    dstE[i] = gidx * 512;
  }
  const int NT = K / 32;
  // prologue: tiles 0,1
  #pragma unroll
  for (int i = 0; i < 6; ++i) stage16(src[i], lds + dstE[i]);
  #pragma unroll
  for (int i = 0; i < 6; ++i) stage16(src[i] + 32, lds + WS_BUFE + dstE[i]);
  int pb = 2;  // (t+2)%3
  for (int t = 0; t < NT; ++t) {
    if (t + 2 < NT) {
      u16* bb = lds + pb * WS_BUFE;
      #pragma unroll
      for (int i = 0; i < 6; ++i) stage16(src[i] + (t + 2) * 32, bb + dstE[i]);
      VMCNT(6);
    } else {
      VMCNT(0);
    }
    SBAR();
    pb = (pb == 2) ? 0 : pb + 1;
  }
}

__device__ __forceinline__ void ws_consumer(int K, const u16* lds, f32x4 acc[4][8]) {
  const int lane = threadIdx.x & 63;
  const int wave = threadIdx.x >> 6;   // 0..3
  const int wr = wave >> 1, wc = wave & 1;
  const int fr = lane & 15, fgrp = lane >> 4;

  int offA[4], offB[8];
  #pragma unroll
  for (int m = 0; m < 4; ++m) {
    const int ra = wr * 64 + m * 16 + fr;
    const int Ra = ra >> 1;
    offA[m] = Ra * 128 + (((((ra & 1) << 2) | fgrp) ^ (Ra & 7)) << 4);
  }
  #pragma unroll
  for (int n = 0; n < 8; ++n) {
    const int rb = wc * 128 + n * 16 + fr;
    const int Rb = rb >> 1;
    offB[n] = WS_ABYT + Rb * 128 + (((((rb & 1) << 2) | fgrp) ^ (Rb & 7)) << 4);
  }

  const f32x4 vzero = {0.f, 0.f, 0.f, 0.f};
  #pragma unroll
  for (int m = 0; m < 4; ++m)
    #pragma unroll
    for (int n = 0; n < 8; ++n)
      acc[m][n] = vzero;

  const int NT = K / 32;
  half8 aE[4], bE[8], aO[4], bO[8];

#define READF(BI, AA, BB)                                                        \
  {                                                                              \
    const char* _b = (const char*)lds + (BI) * (WS_BUFE * 2);                    \
    _Pragma("unroll")                                                            \
    for (int m = 0; m < 4; ++m) AA[m] = *(const half8*)(_b + offA[m]);           \
    _Pragma("unroll")                                                            \
    for (int n = 0; n < 8; ++n) BB[n] = *(const half8*)(_b + offB[n]);           \
  }
#define MFMA_T(AA, BB)                                                           \
  __builtin_amdgcn_s_setprio(1);                                                 \
  _Pragma("unroll")                                                              \
  for (int m = 0; m < 4; ++m)                                                    \
    _Pragma("unroll")                                                            \
    for (int n = 0; n < 8; ++n)                                                  \
      acc[m][n] = __builtin_amdgcn_mfma_f32_16x16x32_f16(AA[m], BB[n],           \
                                                         acc[m][n], 0, 0, 0);    \
  __builtin_amdgcn_s_setprio(0);

  SBAR();                      // bar 0: tiles 0,1 landed (producer vmcnt'd)
  READF(0, aE, bE);
  READF(1, aO, bO);
  MFMA_T(aE, bE);              // tile 0
  LGKM0();
  int ib = 2;                  // (t+1)%3 at t=1
  for (int t = 1; t + 1 < NT; t += 2) {
    SBAR();                    // bar t: tile t+1 landed
    READF(ib, aE, bE);         // tile t+1
    MFMA_T(aO, bO);            // tile t
    LGKM0();
    SBAR();                    // bar t+1: tile t+2 landed
    const int ib2 = (ib == 2) ? 0 : ib + 1;
    if (t + 2 < NT) READF(ib2, aO, bO);   // tile t+2
    MFMA_T(aE, bE);            // tile t+1
    LGKM0();
    ib = (ib2 == 2) ? 0 : ib2 + 1;        // (t+3)%3
  }
  SBAR();                      // bar NT-1
  MFMA_T(aO, bO);              // tile NT-1
#undef READF
#undef MFMA_T
}

// ---------------- projections (r5 core, 128x128): Q/K fp16, V transposed ----------------
__global__ __launch_bounds__(256) void proj_kernel(
    const u16* __restrict__ xh, const u16* __restrict__ Wh,
    const float* __restrict__ bq, const float* __restrict__ bk, const float* __restrict__ bv,
    u16* __restrict__ Qb, u16* __restrict__ Kb, u16* __restrict__ Vt) {
  __shared__ __align__(16) u16 lds[3 * 8192];  // 48 KB
  int bx, by, bz;
  xcd_remap(bx, by, bz);
  const int z  = bz;
  const int m0 = by * 128;
  const int n0 = bx * 128;
  const u16* W = Wh + (size_t)z * D_ * D_;
  const float* bias = (z == 0) ? bq : (z == 1) ? bk : bv;
  f32x4 acc[4][4];
  gemm128(xh, W, D_, m0, n0, lds, acc);

  const int lane = threadIdx.x & 63;
  const int wave = threadIdx.x >> 6;
  const int wr = wave >> 1, wc = wave & 1;
  #pragma unroll
  for (int m = 0; m < 4; ++m) {
    const int gr0 = m0 + wr * 64 + m * 16 + ((lane >> 4) << 2);
    #pragma unroll
    for (int n = 0; n < 4; ++n) {
      const int gc = n0 + wc * 64 + n * 16 + (lane & 15);
      const float bb = bias[gc];
      if (z < 2) {
        u16* O = z ? Kb : Qb;
        #pragma unroll
        for (int r = 0; r < 4; ++r)
          O[(size_t)(gr0 + r) * D_ + gc] = f2h(acc[m][n][r] + bb);
      } else {
        const int bidx = gr0 >> 11;
        const int s    = gr0 & 2047;
        us4 p;
        #pragma unroll
        for (int r = 0; r < 4; ++r) p[r] = f2h(acc[m][n][r] + bb);
        *(us4*)(Vt + ((size_t)bidx * D_ + gc) * S_ + s) = p;
      }
    }
  }
}

// ---------------- QK^T (coreWS, 128x256) -> E fp16 ----------------
__global__ __launch_bounds__(512, 1) void qk_kernel(
    const u16* __restrict__ Qb, const u16* __restrict__ Kb, u16* __restrict__ E,
    size_t sA, size_t sE) {
  __shared__ __align__(16) u16 lds[3 * WS_BUFE];  // 72 KB
  int bx, by, bz;
  xcd_remap(bx, by, bz);
  const int z  = bz;
  const int m0 = by * 128;
  const int n0 = bx * 256;
  const u16* A = Qb + (size_t)z * sA;
  const u16* B = Kb + (size_t)z * sA;
  const int wave = threadIdx.x >> 6;
  if (wave >= 4) { ws_producer(A, B, D_, m0, n0, lds); return; }

  f32x4 acc[4][8];
  ws_consumer(D_, lds, acc);

  u16* Eb = E + (size_t)z * sE;
  const int lane = threadIdx.x & 63;
  const int wr = wave >> 1, wc = wave & 1;
  #pragma unroll
  for (int m = 0; m < 4; ++m) {
    const int gr0 = m0 + wr * 64 + m * 16 + ((lane >> 4) << 2);
    #pragma unroll
    for (int n = 0; n < 8; ++n) {
      const int gc = n0 + wc * 128 + n * 16 + (lane & 15);
      #pragma unroll
      for (int r = 0; r < 4; ++r)
        Eb[(size_t)(gr0 + r) * S_ + gc] = f2h(acc[m][n][r]);
    }
  }
}

// ---------------- row softmax, in place fp16 -> fp16 ----------------
__global__ __launch_bounds__(256) void softmax_kernel(u16* __restrict__ E) {
  const int row  = blockIdx.x * 4 + (threadIdx.x >> 6);
  const int lane = threadIdx.x & 63;
  u16* R = E + (size_t)row * S_;
  float e[32];
  #pragma unroll
  for (int i = 0; i < 4; ++i) {
    ushort8 v = *(const ushort8*)(R + i * 512 + lane * 8);
    #pragma unroll
    for (int j = 0; j < 8; ++j) e[i * 8 + j] = h2f(v[j]);
  }
  float m = e[0];
  #pragma unroll
  for (int i = 1; i < 32; ++i) m = fmaxf(m, e[i]);
  for (int off = 32; off > 0; off >>= 1) m = fmaxf(m, __shfl_xor(m, off, 64));
  float s = 0.f;
  #pragma unroll
  for (int i = 0; i < 32; ++i) { e[i] = __expf(e[i] - m); s += e[i]; }
  for (int off = 32; off > 0; off >>= 1) s += __shfl_xor(s, off, 64);
  const float inv = 1.f / s;
  #pragma unroll
  for (int i = 0; i < 4; ++i) {
    ushort8 v;
    #pragma unroll
    for (int j = 0; j < 8; ++j) v[j] = f2h(e[i * 8 + j] * inv);
    *(ushort8*)(R + i * 512 + lane * 8) = v;
  }
}

// ---------------- PV (coreWS, 128x256) -> fp32 out ----------------
__global__ __launch_bounds__(512, 1) void pv_kernel(
    const u16* __restrict__ P, const u16* __restrict__ Vt, float* __restrict__ out,
    size_t sP, size_t sV, size_t sO) {
  __shared__ __align__(16) u16 lds[3 * WS_BUFE];  // 72 KB
  int bx, by, bz;
  xcd_remap(bx, by, bz);
  const int z  = bz;
  const int m0 = by * 128;
  const int n0 = bx * 256;
  const u16* A = P + (size_t)z * sP;
  const u16* B = Vt + (size_t)z * sV;
  const int wave = threadIdx.x >> 6;
  if (wave >= 4) { ws_producer(A, B, S_, m0, n0, lds); return; }

  f32x4 acc[4][8];
  ws_consumer(S_, lds, acc);

  float* Ob = out + (size_t)z * sO;
  const int lane = threadIdx.x & 63;
  const int wr = wave >> 1, wc = wave & 1;
  #pragma unroll
  for (int m = 0; m < 4; ++m) {
    const int gr0 = m0 + wr * 64 + m * 16 + ((lane >> 4) << 2);
    #pragma unroll
    for (int n = 0; n < 8; ++n) {
      const int gc = n0 + wc * 128 + n * 16 + (lane & 15);
      #pragma unroll
      for (int r = 0; r < 4; ++r)
        Ob[(size_t)(gr0 + r) * D_ + gc] = acc[m][n][r];
    }
  }
}

// ---------------- fp32 -> fp16 converts ----------------
__global__ __launch_bounds__(256) void cvt_kernel(const float* __restrict__ in,
                                                  u16* __restrict__ out, int n8) {
  const int i = blockIdx.x * 256 + threadIdx.x;
  if (i >= n8) return;
  const float4v a = *(const float4v*)(in + (size_t)i * 8);
  const float4v b = *(const float4v*)(in + (size_t)i * 8 + 4);
  ushort8 o;
  o[0] = f2h(a[0]); o[1] = f2h(a[1]); o[2] = f2h(a[2]); o[3] = f2h(a[3]);
  o[4] = f2h(b[0]); o[5] = f2h(b[1]); o[6] = f2h(b[2]); o[7] = f2h(b[3]);
  *(ushort8*)(out + (size_t)i * 8) = o;
}

__global__ __launch_bounds__(256) void cvt3_kernel(const float* __restrict__ w0,
                                                   const float* __restrict__ w1,
                                                   const float* __restrict__ w2,
                                                   u16* __restrict__ out, int n8) {
  const int i = blockIdx.x * 256 + threadIdx.x;
  if (i >= n8) return;
  const float* in = (blockIdx.y == 0) ? w0 : (blockIdx.y == 1) ? w1 : w2;
  u16* o_ = out + (size_t)blockIdx.y * D_ * D_;
  const float4v a = *(const float4v*)(in + (size_t)i * 8);
  const float4v b = *(const float4v*)(in + (size_t)i * 8 + 4);
  ushort8 o;
  o[0] = f2h(a[0]); o[1] = f2h(a[1]); o[2] = f2h(a[2]); o[3] = f2h(a[3]);
  o[4] = f2h(b[0]); o[5] = f2h(b[1]); o[6] = f2h(b[2]); o[7] = f2h(b[3]);
  *(ushort8*)(o_ + (size_t)i * 8) = o;
}

extern "C" void kernel_launch(void* const* d_in, const int* in_sizes, int n_in,
                              void* d_out, int out_size, void* d_ws, size_t ws_size,
                              hipStream_t stream) {
  (void)in_sizes; (void)n_in; (void)out_size;
  const float* x  = (const float*)d_in[0];
  const float* Wq = (const float*)d_in[1];
  const float* bq = (const float*)d_in[2];
  const float* Wk = (const float*)d_in[3];
  const float* bk = (const float*)d_in[4];
  const float* Wv = (const float*)d_in[5];
  const float* bv = (const float*)d_in[6];
  float* out = (float*)d_out;

  char* ws = (char*)d_ws;
  size_t off = 0;
  auto alloc = [&](size_t bytes) -> char* {
    char* p = ws + off;
    off += (bytes + 255) & ~(size_t)255;
    return p;
  };
  const size_t MS = (size_t)B_ * S_;  // 16384 rows total
  u16* xh = (u16*)alloc(MS * D_ * 2);
  u16* Wh = (u16*)alloc(3ull * D_ * D_ * 2);
  u16* Qb = (u16*)alloc(MS * D_ * 2);
  u16* Kb = (u16*)alloc(MS * D_ * 2);
  u16* Vt = (u16*)alloc(MS * D_ * 2);
  const size_t Efull = (size_t)B_ * S_ * S_ * 2;
  const bool full = ws_size >= off + Efull;  // ~136 MB total; else per-batch E
  u16* E = (u16*)alloc(full ? Efull : (size_t)S_ * S_ * 2);

  // fp32 -> fp16 converts
  {
    const int n8 = (int)(MS * D_ / 8);
    cvt_kernel<<<dim3((n8 + 255) / 256), dim3(256), 0, stream>>>(x, xh, n8);
    const int w8 = D_ * D_ / 8;
    cvt3_kernel<<<dim3((w8 + 255) / 256, 3), dim3(256), 0, stream>>>(Wq, Wk, Wv, Wh, w8);
  }

  // Q/K/V projections (z = 0/1/2), 128x128 tiles (r5 core)
  proj_kernel<<<dim3(D_ / 128, MS / 128, 3), dim3(256), 0, stream>>>(
      xh, Wh, bq, bk, bv, Qb, Kb, Vt);

  if (full) {
    qk_kernel<<<dim3(S_ / 256, S_ / 128, B_), dim3(512), 0, stream>>>(
        Qb, Kb, E, (size_t)S_ * D_, (size_t)S_ * S_);
    softmax_kernel<<<dim3(B_ * S_ / 4), dim3(256), 0, stream>>>(E);
    pv_kernel<<<dim3(D_ / 256, S_ / 128, B_), dim3(512), 0, stream>>>(
        E, Vt, out, (size_t)S_ * S_, (size_t)D_ * S_, (size_t)S_ * D_);
  } else {
    for (int b = 0; b < B_; ++b) {
      qk_kernel<<<dim3(S_ / 256, S_ / 128, 1), dim3(512), 0, stream>>>(
          Qb + (size_t)b * S_ * D_, Kb + (size_t)b * S_ * D_, E, 0, 0);
      softmax_kernel<<<dim3(S_ / 4), dim3(256), 0, stream>>>(E);
      pv_kernel<<<dim3(D_ / 256, S_ / 128, 1), dim3(512), 0, stream>>>(
          E, Vt + (size_t)b * D_ * S_, out + (size_t)b * S_ * D_, 0, 0, 0);
    }
  }
}

// Round 15
// 155.896 us; speedup vs baseline: 1.1068x; 1.1068x over previous
//
#include <hip/hip_runtime.h>

typedef unsigned short u16;
typedef _Float16 f16;

using half8   = __attribute__((ext_vector_type(8))) _Float16;
using f32x4   = __attribute__((ext_vector_type(4))) float;
using ushort8 = __attribute__((ext_vector_type(8))) unsigned short;
using us4     = __attribute__((ext_vector_type(4))) unsigned short;
using float4v = __attribute__((ext_vector_type(4))) float;

#define B_  8
#define S_  2048
#define D_  512

#define VMCNT(N)  asm volatile("s_waitcnt vmcnt(" #N ")" ::: "memory")
#define SBAR()    asm volatile("s_barrier" ::: "memory")

__device__ __forceinline__ u16 f2h(float f) {
  f16 h = (f16)f;
  u16 u;
  __builtin_memcpy(&u, &h, 2);
  return u;
}

__device__ __forceinline__ float h2f(u16 h) {
  f16 x;
  __builtin_memcpy(&x, &h, 2);
  return (float)x;
}

__device__ __forceinline__ void stage16(const void* g, void* l) {
  __builtin_amdgcn_global_load_lds((const __attribute__((address_space(1))) void*)g,
                                   (__attribute__((address_space(3))) void*)l,
                                   16, 0, 0);
}

// XCD-aware bijective remap (all grids have nwg % 8 == 0).
__device__ __forceinline__ void xcd_remap(int& bx, int& by, int& bz) {
  const int lin = ((int)blockIdx.z * (int)gridDim.y + (int)blockIdx.y) * (int)gridDim.x
                  + (int)blockIdx.x;
  const int nwg = (int)gridDim.x * (int)gridDim.y * (int)gridDim.z;
  const int swz = (lin & 7) * (nwg >> 3) + (lin >> 3);
  bx = swz % (int)gridDim.x;
  const int tmp = swz / (int)gridDim.x;
  by = tmp % (int)gridDim.y;
  bz = tmp / (int)gridDim.y;
}

// ===================== round-5 core: 128x128, BK=32, 3-buf (proj) =====================
__device__ __forceinline__ void gemm128(const u16* __restrict__ A, const u16* __restrict__ B,
                                        int K, int m0, int n0,
                                        u16* lds, f32x4 acc[4][4]) {
  constexpr int TILE_ELEMS = 4096;
  constexpr int BUF_ELEMS  = 8192;
  const int tid  = threadIdx.x;
  const int lane = tid & 63;
  const int wave = tid >> 6;
  const int wr = wave >> 1, wc = wave & 1;
  const int fr   = lane & 15;
  const int fgrp = lane >> 4;

  int sr[2], sc[2];
  #pragma unroll
  for (int s = 0; s < 2; ++s) {
    const int p    = tid * 16 + s * 4096;
    const int R    = p >> 7;
    const int slot = (p >> 4) & 7;
    const int s0   = slot ^ (R & 7);
    sr[s] = 2 * R + (s0 >> 2);
    sc[s] = (s0 & 3) * 8;
  }

  int offA[4], offB[4];
  #pragma unroll
  for (int m = 0; m < 4; ++m) {
    const int ra = wr * 64 + m * 16 + fr;
    const int Ra = ra >> 1;
    offA[m] = Ra * 128 + (((((ra & 1) << 2) | fgrp) ^ (Ra & 7)) << 4);
    const int rb = wc * 64 + m * 16 + fr;
    const int Rb = rb >> 1;
    offB[m] = Rb * 128 + (((((rb & 1) << 2) | fgrp) ^ (Rb & 7)) << 4);
  }

  const f32x4 vzero = {0.f, 0.f, 0.f, 0.f};
  #pragma unroll
  for (int m = 0; m < 4; ++m)
    #pragma unroll
    for (int n = 0; n < 4; ++n)
      acc[m][n] = vzero;

  const int T = K / 32;

  auto STAGE = [&](int t, u16* buf) {
    #pragma unroll
    for (int s = 0; s < 2; ++s) {
      stage16(A + (size_t)(m0 + sr[s]) * K + t * 32 + sc[s],
              buf + s * 2048 + wave * 512);
      stage16(B + (size_t)(n0 + sr[s]) * K + t * 32 + sc[s],
              buf + TILE_ELEMS + s * 2048 + wave * 512);
    }
  };

  STAGE(0, lds);
  STAGE(1, lds + BUF_ELEMS);

  int r = 0;
  for (int u = 0; u < T; ++u) {
    if (u + 1 < T) {
      asm volatile("s_waitcnt vmcnt(4)\n\ts_barrier" ::: "memory");
    } else {
      asm volatile("s_waitcnt vmcnt(0)\n\ts_barrier" ::: "memory");
    }
    const u16* buf = lds + r * BUF_ELEMS;
    half8 a[4], b[4];
    #pragma unroll
    for (int m = 0; m < 4; ++m)
      a[m] = *(const half8*)((const char*)buf + offA[m]);
    #pragma unroll
    for (int n = 0; n < 4; ++n)
      b[n] = *(const half8*)((const char*)(buf + TILE_ELEMS) + offB[n]);
    if (u + 2 < T)
      STAGE(u + 2, lds + (r == 0 ? 2 : r - 1) * BUF_ELEMS);
    __builtin_amdgcn_s_setprio(1);
    #pragma unroll
    for (int m = 0; m < 4; ++m)
      #pragma unroll
      for (int n = 0; n < 4; ++n)
        acc[m][n] = __builtin_amdgcn_mfma_f32_16x16x32_f16(a[m], b[n], acc[m][n], 0, 0, 0);
    __builtin_amdgcn_s_setprio(0);
    r = (r == 2) ? 0 : r + 1;
  }
}

// ===================== core4ra: 4-phase read-ahead, BM x 256, BK=64 (qk, pv) =====================
// (round-13 verified: 156.0 us total composition)
template<int M_REP>
__device__ __forceinline__ void core4ra(const u16* __restrict__ A,
                                        const u16* __restrict__ B,
                                        int K, int m0, int n0,
                                        u16* lds, f32x4 acc[M_REP][4]) {
  constexpr int M2   = M_REP / 2;
  constexpr int BM   = M_REP * 32;
  constexpr int AIS  = BM * 32;
  constexpr int BOFF = BM * 64;
  constexpr int BUFE = BM * 64 + 16384;
  constexpr int ASL  = BM / 128;
  constexpr int QSRA = (BM == 256) ? 32 : 16;

  const int tid  = threadIdx.x;
  const int lane = tid & 63;
  const int wave = tid >> 6;
  const int wr = wave >> 2, wc = wave & 3;
  const int fr = lane & 15, fgrp = lane >> 4;

  int    dstA[2][ASL];  size_t gA[2][ASL];
  int    dstB[2][2];    size_t gB[2][2];
  #pragma unroll
  for (int q = 0; q < 2; ++q) {
    #pragma unroll
    for (int s = 0; s < ASL; ++s) {
      int ks, jr;
      if constexpr (ASL == 2) { ks = s; jr = wave * 8; }
      else                    { ks = wave >> 2; jr = (wave & 3) * 8; }
      const int R   = (jr / QSRA) * (2 * QSRA) + q * QSRA + (jr % QSRA);
      const int dst = ks * AIS + R * 64;
      dstA[q][s] = dst;
      const int e   = dst + lane * 8;
      const int ks2 = e / AIS, le = e - ks2 * AIS;
      const int RR  = le >> 6;
      const int s0  = ((le >> 3) & 7) ^ (RR & 7);
      gA[q][s] = (size_t)(m0 + 2 * RR + (s0 >> 2)) * K + ks2 * 32 + (s0 & 3) * 8;
    }
    #pragma unroll
    for (int s = 0; s < 2; ++s) {
      const int jr  = wave * 8;
      const int R   = (jr / 16) * 32 + q * 16 + (jr % 16);
      const int dst = BOFF + s * 8192 + R * 64;
      dstB[q][s] = dst;
      const int e   = dst - BOFF + lane * 8;
      const int ks2 = e / 8192, le = e - ks2 * 8192;
      const int RR  = le >> 6;
      const int s0  = ((le >> 3) & 7) ^ (RR & 7);
      gB[q][s] = (size_t)(n0 + 2 * RR + (s0 >> 2)) * K + ks2 * 32 + (s0 & 3) * 8;
    }
  }

  int offA[2][M2][2], offB[2][2][2];
  #pragma unroll
  for (int mh = 0; mh < 2; ++mh)
    #pragma unroll
    for (int m = 0; m < M2; ++m)
      #pragma unroll
      for (int ks = 0; ks < 2; ++ks) {
        const int ra = wr * (M_REP * 16) + (mh * M2 + m) * 16 + fr;
        const int Ra = ra >> 1;
        offA[mh][m][ks] = (ks * AIS + Ra * 64) * 2 +
                          (((((ra & 1) << 2) | fgrp) ^ (Ra & 7)) << 4);
      }
  #pragma unroll
  for (int nh = 0; nh < 2; ++nh)
    #pragma unroll
    for (int n = 0; n < 2; ++n)
      #pragma unroll
      for (int ks = 0; ks < 2; ++ks) {
        const int rb = wc * 64 + (nh * 2 + n) * 16 + fr;
        const int Rb = rb >> 1;
        offB[nh][n][ks] = (BOFF + ks * 8192 + Rb * 64) * 2 +
                          (((((rb & 1) << 2) | fgrp) ^ (Rb & 7)) << 4);
      }

  const f32x4 vzero = {0.f, 0.f, 0.f, 0.f};
  #pragma unroll
  for (int m = 0; m < M_REP; ++m)
    #pragma unroll
    for (int n = 0; n < 4; ++n)
      acc[m][n] = vzero;

  const int NT = K >> 6;

  auto stageA = [&](int q, int tt) {
    u16* bb = lds + (tt & 1) * BUFE;
    #pragma unroll
    for (int s = 0; s < ASL; ++s)
      stage16(A + gA[q][s] + (size_t)tt * 64, bb + dstA[q][s]);
  };
  auto stageB = [&](int q, int tt) {
    u16* bb = lds + (tt & 1) * BUFE;
    #pragma unroll
    for (int s = 0; s < 2; ++s)
      stage16(B + gB[q][s] + (size_t)tt * 64, bb + dstB[q][s]);
  };

  // prologue: tiles 0 and 1 fully staged (queue order Aq0,Bq0,Bq1,Aq1 per tile)
  stageA(0, 0); stageB(0, 0); stageB(1, 0); stageA(1, 0);
  stageA(0, 1); stageB(0, 1); stageB(1, 1); stageA(1, 1);

  half8 a0[M2][2], a1[M2][2], blo[2][2], bhi[2][2];

  // prologue gate + first read-ahead
  if constexpr (ASL == 2) VMCNT(12); else VMCNT(9);
  SBAR();
  {
    const char* rb0 = (const char*)lds;
    #pragma unroll
    for (int m = 0; m < M2; ++m)
      #pragma unroll
      for (int ks = 0; ks < 2; ++ks)
        a0[m][ks] = *(const half8*)(rb0 + offA[0][m][ks]);
    #pragma unroll
    for (int n = 0; n < 2; ++n)
      #pragma unroll
      for (int ks = 0; ks < 2; ++ks)
        blo[n][ks] = *(const half8*)(rb0 + offB[0][n][ks]);
  }
  if constexpr (ASL == 2) VMCNT(10); else VMCNT(7);

#define MFMA_Q(AA, BB, MH, NB)                                                   \
  __builtin_amdgcn_s_setprio(1);                                                 \
  _Pragma("unroll")                                                              \
  for (int m = 0; m < M2; ++m)                                                   \
    _Pragma("unroll")                                                            \
    for (int n = 0; n < 2; ++n)                                                  \
      _Pragma("unroll")                                                          \
      for (int ks = 0; ks < 2; ++ks)                                             \
        acc[(MH) * M2 + m][(NB) + n] = __builtin_amdgcn_mfma_f32_16x16x32_f16(   \
            AA[m][ks], BB[n][ks], acc[(MH) * M2 + m][(NB) + n], 0, 0, 0);        \
  __builtin_amdgcn_s_setprio(0);

  for (int t = 0; t < NT; ++t) {
    const char* rb_  = (const char*)(lds + (t & 1) * BUFE);
    const char* rbn_ = (const char*)(lds + ((t + 1) & 1) * BUFE);

    // ---- P0 ----
    SBAR();
    MFMA_Q(a0, blo, 0, 0)
    #pragma unroll
    for (int n = 0; n < 2; ++n)
      #pragma unroll
      for (int ks = 0; ks < 2; ++ks)
        bhi[n][ks] = *(const half8*)(rb_ + offB[1][n][ks]);
    if (t == NT - 1) VMCNT(0);
    else if constexpr (ASL == 2) VMCNT(8); else VMCNT(6);

    // ---- P1 ----
    SBAR();
    MFMA_Q(a0, bhi, 0, 2)
    #pragma unroll
    for (int m = 0; m < M2; ++m)
      #pragma unroll
      for (int ks = 0; ks < 2; ++ks)
        a1[m][ks] = *(const half8*)(rb_ + offA[1][m][ks]);
    if (t + 2 < NT) { stageA(0, t + 2); stageB(0, t + 2); }

    // ---- P2 ----
    SBAR();
    MFMA_Q(a1, bhi, 1, 2)
    if (t + 2 < NT) stageB(1, t + 2);
    if (t + 1 < NT) {
      if (t + 2 < NT) { if constexpr (ASL == 2) VMCNT(10); else VMCNT(8); }
      else            { if constexpr (ASL == 2) VMCNT(4);  else VMCNT(3); }
    }

    // ---- P3 ----
    SBAR();
    MFMA_Q(a1, blo, 1, 0)
    if (t + 1 < NT) {
      #pragma unroll
      for (int m = 0; m < M2; ++m)
        #pragma unroll
        for (int ks = 0; ks < 2; ++ks)
          a0[m][ks] = *(const half8*)(rbn_ + offA[0][m][ks]);
      #pragma unroll
      for (int n = 0; n < 2; ++n)
        #pragma unroll
        for (int ks = 0; ks < 2; ++ks)
          blo[n][ks] = *(const half8*)(rbn_ + offB[0][n][ks]);
      if (t + 2 < NT) {
        stageA(1, t + 2);
        if constexpr (ASL == 2) VMCNT(10); else VMCNT(7);
      } else {
        if constexpr (ASL == 2) VMCNT(2); else VMCNT(1);
      }
    }
  }
#undef MFMA_Q
}

// ---------------- projections (r5 core, 128x128): Q/K fp16, V transposed ----------------
__global__ __launch_bounds__(256) void proj_kernel(
    const u16* __restrict__ xh, const u16* __restrict__ Wh,
    const float* __restrict__ bq, const float* __restrict__ bk, const float* __restrict__ bv,
    u16* __restrict__ Qb, u16* __restrict__ Kb, u16* __restrict__ Vt) {
  __shared__ __align__(16) u16 lds[3 * 8192];  // 48 KB
  int bx, by, bz;
  xcd_remap(bx, by, bz);
  const int z  = bz;
  const int m0 = by * 128;
  const int n0 = bx * 128;
  const u16* W = Wh + (size_t)z * D_ * D_;
  const float* bias = (z == 0) ? bq : (z == 1) ? bk : bv;
  f32x4 acc[4][4];
  gemm128(xh, W, D_, m0, n0, lds, acc);

  const int lane = threadIdx.x & 63;
  const int wave = threadIdx.x >> 6;
  const int wr = wave >> 1, wc = wave & 1;
  #pragma unroll
  for (int m = 0; m < 4; ++m) {
    const int gr0 = m0 + wr * 64 + m * 16 + ((lane >> 4) << 2);
    #pragma unroll
    for (int n = 0; n < 4; ++n) {
      const int gc = n0 + wc * 64 + n * 16 + (lane & 15);
      const float bb = bias[gc];
      if (z < 2) {
        u16* O = z ? Kb : Qb;
        #pragma unroll
        for (int r = 0; r < 4; ++r)
          O[(size_t)(gr0 + r) * D_ + gc] = f2h(acc[m][n][r] + bb);
      } else {
        const int bidx = gr0 >> 11;
        const int s    = gr0 & 2047;
        us4 p;
        #pragma unroll
        for (int r = 0; r < 4; ++r) p[r] = f2h(acc[m][n][r] + bb);
        *(us4*)(Vt + ((size_t)bidx * D_ + gc) * S_ + s) = p;
      }
    }
  }
}

// ---------------- QK^T (core4ra, 256x256) -> E fp16 ----------------
__global__ __launch_bounds__(512, 1) void qk_kernel(
    const u16* __restrict__ Qb, const u16* __restrict__ Kb, u16* __restrict__ E,
    size_t sA, size_t sE) {
  __shared__ __align__(16) u16 lds[2 * (256 * 64 + 16384)];  // 128 KB
  int bx, by, bz;
  xcd_remap(bx, by, bz);
  const int z  = bz;
  const int m0 = by * 256;
  const int n0 = bx * 256;
  f32x4 acc[8][4];
  core4ra<8>(Qb + (size_t)z * sA, Kb + (size_t)z * sA, D_, m0, n0, lds, acc);

  u16* Eb = E + (size_t)z * sE;
  const int lane = threadIdx.x & 63;
  const int wave = threadIdx.x >> 6;
  const int wr = wave >> 2, wc = wave & 3;
  #pragma unroll
  for (int m = 0; m < 8; ++m) {
    const int gr0 = m0 + wr * 128 + m * 16 + ((lane >> 4) << 2);
    #pragma unroll
    for (int n = 0; n < 4; ++n) {
      const int gc = n0 + wc * 64 + n * 16 + (lane & 15);
      #pragma unroll
      for (int r = 0; r < 4; ++r)
        Eb[(size_t)(gr0 + r) * S_ + gc] = f2h(acc[m][n][r]);
    }
  }
}

// ---------------- row softmax, in place fp16 -> fp16 ----------------
__global__ __launch_bounds__(256) void softmax_kernel(u16* __restrict__ E) {
  const int row  = blockIdx.x * 4 + (threadIdx.x >> 6);
  const int lane = threadIdx.x & 63;
  u16* R = E + (size_t)row * S_;
  float e[32];
  #pragma unroll
  for (int i = 0; i < 4; ++i) {
    ushort8 v = *(const ushort8*)(R + i * 512 + lane * 8);
    #pragma unroll
    for (int j = 0; j < 8; ++j) e[i * 8 + j] = h2f(v[j]);
  }
  float m = e[0];
  #pragma unroll
  for (int i = 1; i < 32; ++i) m = fmaxf(m, e[i]);
  for (int off = 32; off > 0; off >>= 1) m = fmaxf(m, __shfl_xor(m, off, 64));
  float s = 0.f;
  #pragma unroll
  for (int i = 0; i < 32; ++i) { e[i] = __expf(e[i] - m); s += e[i]; }
  for (int off = 32; off > 0; off >>= 1) s += __shfl_xor(s, off, 64);
  const float inv = 1.f / s;
  #pragma unroll
  for (int i = 0; i < 4; ++i) {
    ushort8 v;
    #pragma unroll
    for (int j = 0; j < 8; ++j) v[j] = f2h(e[i * 8 + j] * inv);
    *(ushort8*)(R + i * 512 + lane * 8) = v;
  }
}

// ---------------- PV (core4ra, 128x256) -> fp32 out ----------------
__global__ __launch_bounds__(512, 1) void pv_kernel(
    const u16* __restrict__ P, const u16* __restrict__ Vt, float* __restrict__ out,
    size_t sP, size_t sV, size_t sO) {
  __shared__ __align__(16) u16 lds[2 * (128 * 64 + 16384)];  // 96 KB
  int bx, by, bz;
  xcd_remap(bx, by, bz);
  const int z  = bz;
  const int m0 = by * 128;
  const int n0 = bx * 256;
  f32x4 acc[4][4];
  core4ra<4>(P + (size_t)z * sP, Vt + (size_t)z * sV, S_, m0, n0, lds, acc);

  float* Ob = out + (size_t)z * sO;
  const int lane = threadIdx.x & 63;
  const int wave = threadIdx.x >> 6;
  const int wr = wave >> 2, wc = wave & 3;
  #pragma unroll
  for (int m = 0; m < 4; ++m) {
    const int gr0 = m0 + wr * 64 + m * 16 + ((lane >> 4) << 2);
    #pragma unroll
    for (int n = 0; n < 4; ++n) {
      const int gc = n0 + wc * 64 + n * 16 + (lane & 15);
      #pragma unroll
      for (int r = 0; r < 4; ++r)
        Ob[(size_t)(gr0 + r) * D_ + gc] = acc[m][n][r];
    }
  }
}

// ---------------- fp32 -> fp16 converts ----------------
__global__ __launch_bounds__(256) void cvt_kernel(const float* __restrict__ in,
                                                  u16* __restrict__ out, int n8) {
  const int i = blockIdx.x * 256 + threadIdx.x;
  if (i >= n8) return;
  const float4v a = *(const float4v*)(in + (size_t)i * 8);
  const float4v b = *(const float4v*)(in + (size_t)i * 8 + 4);
  ushort8 o;
  o[0] = f2h(a[0]); o[1] = f2h(a[1]); o[2] = f2h(a[2]); o[3] = f2h(a[3]);
  o[4] = f2h(b[0]); o[5] = f2h(b[1]); o[6] = f2h(b[2]); o[7] = f2h(b[3]);
  *(ushort8*)(out + (size_t)i * 8) = o;
}

__global__ __launch_bounds__(256) void cvt3_kernel(const float* __restrict__ w0,
                                                   const float* __restrict__ w1,
                                                   const float* __restrict__ w2,
                                                   u16* __restrict__ out, int n8) {
  const int i = blockIdx.x * 256 + threadIdx.x;
  if (i >= n8) return;
  const float* in = (blockIdx.y == 0) ? w0 : (blockIdx.y == 1) ? w1 : w2;
  u16* o_ = out + (size_t)blockIdx.y * D_ * D_;
  const float4v a = *(const float4v*)(in + (size_t)i * 8);
  const float4v b = *(const float4v*)(in + (size_t)i * 8 + 4);
  ushort8 o;
  o[0] = f2h(a[0]); o[1] = f2h(a[1]); o[2] = f2h(a[2]); o[3] = f2h(a[3]);
  o[4] = f2h(b[0]); o[5] = f2h(b[1]); o[6] = f2h(b[2]); o[7] = f2h(b[3]);
  *(ushort8*)(o_ + (size_t)i * 8) = o;
}

extern "C" void kernel_launch(void* const* d_in, const int* in_sizes, int n_in,
                              void* d_out, int out_size, void* d_ws, size_t ws_size,
                              hipStream_t stream) {
  (void)in_sizes; (void)n_in; (void)out_size;
  const float* x  = (const float*)d_in[0];
  const float* Wq = (const float*)d_in[1];
  const float* bq = (const float*)d_in[2];
  const float* Wk = (const float*)d_in[3];
  const float* bk = (const float*)d_in[4];
  const float* Wv = (const float*)d_in[5];
  const float* bv = (const float*)d_in[6];
  float* out = (float*)d_out;

  char* ws = (char*)d_ws;
  size_t off = 0;
  auto alloc = [&](size_t bytes) -> char* {
    char* p = ws + off;
    off += (bytes + 255) & ~(size_t)255;
    return p;
  };
  const size_t MS = (size_t)B_ * S_;  // 16384 rows total
  u16* xh = (u16*)alloc(MS * D_ * 2);
  u16* Wh = (u16*)alloc(3ull * D_ * D_ * 2);
  u16* Qb = (u16*)alloc(MS * D_ * 2);
  u16* Kb = (u16*)alloc(MS * D_ * 2);
  u16* Vt = (u16*)alloc(MS * D_ * 2);
  const size_t Efull = (size_t)B_ * S_ * S_ * 2;
  const bool full = ws_size >= off + Efull;  // ~136 MB total; else per-batch E
  u16* E = (u16*)alloc(full ? Efull : (size_t)S_ * S_ * 2);

  // fp32 -> fp16 converts
  {
    const int n8 = (int)(MS * D_ / 8);
    cvt_kernel<<<dim3((n8 + 255) / 256), dim3(256), 0, stream>>>(x, xh, n8);
    const int w8 = D_ * D_ / 8;
    cvt3_kernel<<<dim3((w8 + 255) / 256, 3), dim3(256), 0, stream>>>(Wq, Wk, Wv, Wh, w8);
  }

  // Q/K/V projections (z = 0/1/2), 128x128 tiles (r5 core)
  proj_kernel<<<dim3(D_ / 128, MS / 128, 3), dim3(256), 0, stream>>>(
      xh, Wh, bq, bk, bv, Qb, Kb, Vt);

  if (full) {
    qk_kernel<<<dim3(S_ / 256, S_ / 256, B_), dim3(512), 0, stream>>>(
        Qb, Kb, E, (size_t)S_ * D_, (size_t)S_ * S_);
    softmax_kernel<<<dim3(B_ * S_ / 4), dim3(256), 0, stream>>>(E);
    pv_kernel<<<dim3(D_ / 256, S_ / 128, B_), dim3(512), 0, stream>>>(
        E, Vt, out, (size_t)S_ * S_, (size_t)D_ * S_, (size_t)S_ * D_);
  } else {
    for (int b = 0; b < B_; ++b) {
      qk_kernel<<<dim3(S_ / 256, S_ / 256, 1), dim3(512), 0, stream>>>(
          Qb + (size_t)b * S_ * D_, Kb + (size_t)b * S_ * D_, E, 0, 0);
      softmax_kernel<<<dim3(S_ / 4), dim3(256), 0, stream>>>(E);
      pv_kernel<<<dim3(D_ / 256, S_ / 128, 1), dim3(512), 0, stream>>>(
          E, Vt + (size_t)b * D_ * S_, out + (size_t)b * S_ * D_, 0, 0, 0);
    }
  }
}